// Round 8
// baseline (232.776 us; speedup 1.0000x reference)
//
#include <hip/hip_runtime.h>

// GCN 2-layer via CSR gather. k_place ILP-vectorized (4 edges/thread);
// gemm32 fused into gather1 epilogue (in-wave shfl-broadcast row @ LDS W2).
// GEMM k-loops kept ROLLED (#pragma unroll 1): full unroll -> 512 VGPR spill storm.
constexpr int N  = 100000;
constexpr int E  = 800000;
constexpr int CHUNK = 1024;
constexpr int NB = (N + CHUNK - 1) / CHUNK;   // 98 scan blocks

// ---------------- degree (4 edges/thread) ----------------
__global__ void k_degree(const int* __restrict__ dst, int* __restrict__ deg) {
    int t = blockIdx.x * blockDim.x + threadIdx.x;
    int e = t * 4;
    if (e + 3 < E) {
        int4 d4 = *(const int4*)(dst + e);
        atomicAdd(&deg[d4.x], 1);
        atomicAdd(&deg[d4.y], 1);
        atomicAdd(&deg[d4.z], 1);
        atomicAdd(&deg[d4.w], 1);
    } else {
        for (int k = e; k < E; ++k) atomicAdd(&deg[dst[k]], 1);
    }
}

// ---------------- exclusive scan of deg -> rowptr ----------------
__global__ void k_scanA(const int* __restrict__ deg, int* __restrict__ rowptr,
                        int* __restrict__ bsum) {
    __shared__ int a[2][256];
    int b = blockIdx.x, t = threadIdx.x;
    int base = b * CHUNK + t * 4;
    int v[4];
#pragma unroll
    for (int k = 0; k < 4; ++k) v[k] = (base + k < N) ? deg[base + k] : 0;
    int mysum = v[0] + v[1] + v[2] + v[3];
    a[0][t] = mysum;
    __syncthreads();
    int pin = 0;
    for (int off = 1; off < 256; off <<= 1) {
        int x = a[pin][t];
        if (t >= off) x += a[pin][t - off];
        a[pin ^ 1][t] = x;
        __syncthreads();
        pin ^= 1;
    }
    int incl = a[pin][t];
    int run = incl - mysum;
#pragma unroll
    for (int k = 0; k < 4; ++k) {
        if (base + k < N) rowptr[base + k] = run;
        run += v[k];
    }
    if (t == 255) bsum[b] = incl;
}

// scanC: adds global chunk offset (computed in-block from bsum), writes cursor + dis
__global__ void k_scanC(int* __restrict__ rowptr, const int* __restrict__ bsum,
                        int* __restrict__ cursor, const int* __restrict__ deg,
                        float* __restrict__ dis) {
    __shared__ int s_off;
    int cid = blockIdx.x >> 2;            // 256-node block -> 1024-node chunk
    if (threadIdx.x == 0) {
        int run = 0;
        for (int i = 0; i < cid; ++i) run += bsum[i];
        s_off = run;
    }
    __syncthreads();
    int i = blockIdx.x * blockDim.x + threadIdx.x;
    if (i < N) {
        int r = rowptr[i] + s_off;
        rowptr[i] = r;
        cursor[i] = r;
        dis[i] = rsqrtf((float)(deg[i] + 1));   // +1 self-loop
    }
}

// ---------------- CSR placement: 4 edges/thread, 4 independent atomic chains --
__global__ void k_place(const int* __restrict__ src, const int* __restrict__ dst,
                        int* __restrict__ cursor, int* __restrict__ ecol) {
    int t = blockIdx.x * blockDim.x + threadIdx.x;
    int e = t * 4;
    if (e + 3 < E) {
        int4 s4 = *(const int4*)(src + e);
        int4 d4 = *(const int4*)(dst + e);
        int p0 = atomicAdd(&cursor[d4.x], 1);
        int p1 = atomicAdd(&cursor[d4.y], 1);
        int p2 = atomicAdd(&cursor[d4.z], 1);
        int p3 = atomicAdd(&cursor[d4.w], 1);
        ecol[p0] = s4.x;
        ecol[p1] = s4.y;
        ecol[p2] = s4.z;
        ecol[p3] = s4.w;
    } else {
        for (int k = e; k < E; ++k) {
            int pos = atomicAdd(&cursor[dst[k]], 1);
            ecol[pos] = src[k];
        }
    }
}

// ---------------- GEMM 64->64: H[N,64] = X[N,64] @ W[64,64] ----------------
__global__ __launch_bounds__(256, 2)
void k_gemm64(const float* __restrict__ X, const float* __restrict__ W,
              float* __restrict__ H) {
    __shared__ float sX[64][68];    // 272B rows: float4-aligned, 2-way banks (free)
    __shared__ float sW[64 * 64];
    int row0 = blockIdx.x * 64;
    for (int i = threadIdx.x; i < 64 * 64; i += 256) sW[i] = W[i];
    for (int i4 = threadIdx.x; i4 < 64 * 16; i4 += 256) {
        int r = i4 >> 4, c4 = i4 & 15;
        int gr = row0 + r;
        float4 v = make_float4(0.f, 0.f, 0.f, 0.f);
        if (gr < N) v = *(const float4*)(X + (long)gr * 64 + c4 * 4);
        *(float4*)&sX[r][c4 * 4] = v;
    }
    __syncthreads();

    int ty = threadIdx.x >> 4, tx = threadIdx.x & 15;
    int r0 = ty * 4, c0 = tx * 4;
    float4 acc0 = make_float4(0.f, 0.f, 0.f, 0.f);
    float4 acc1 = acc0, acc2 = acc0, acc3 = acc0;

#pragma unroll 1
    for (int k = 0; k < 64; k += 4) {
        float4 a0 = *(const float4*)&sX[r0 + 0][k];
        float4 a1 = *(const float4*)&sX[r0 + 1][k];
        float4 a2 = *(const float4*)&sX[r0 + 2][k];
        float4 a3 = *(const float4*)&sX[r0 + 3][k];
        float4 b0 = *(const float4*)&sW[(k + 0) * 64 + c0];
        float4 b1 = *(const float4*)&sW[(k + 1) * 64 + c0];
        float4 b2 = *(const float4*)&sW[(k + 2) * 64 + c0];
        float4 b3 = *(const float4*)&sW[(k + 3) * 64 + c0];
        acc0.x += a0.x*b0.x + a0.y*b1.x + a0.z*b2.x + a0.w*b3.x;
        acc0.y += a0.x*b0.y + a0.y*b1.y + a0.z*b2.y + a0.w*b3.y;
        acc0.z += a0.x*b0.z + a0.y*b1.z + a0.z*b2.z + a0.w*b3.z;
        acc0.w += a0.x*b0.w + a0.y*b1.w + a0.z*b2.w + a0.w*b3.w;
        acc1.x += a1.x*b0.x + a1.y*b1.x + a1.z*b2.x + a1.w*b3.x;
        acc1.y += a1.x*b0.y + a1.y*b1.y + a1.z*b2.y + a1.w*b3.y;
        acc1.z += a1.x*b0.z + a1.y*b1.z + a1.z*b2.z + a1.w*b3.z;
        acc1.w += a1.x*b0.w + a1.y*b1.w + a1.z*b2.w + a1.w*b3.w;
        acc2.x += a2.x*b0.x + a2.y*b1.x + a2.z*b2.x + a2.w*b3.x;
        acc2.y += a2.x*b0.y + a2.y*b1.y + a2.z*b2.y + a2.w*b3.y;
        acc2.z += a2.x*b0.z + a2.y*b1.z + a2.z*b2.z + a2.w*b3.z;
        acc2.w += a2.x*b0.w + a2.y*b1.w + a2.z*b2.w + a2.w*b3.w;
        acc3.x += a3.x*b0.x + a3.y*b1.x + a3.z*b2.x + a3.w*b3.x;
        acc3.y += a3.x*b0.y + a3.y*b1.y + a3.z*b2.y + a3.w*b3.y;
        acc3.z += a3.x*b0.z + a3.y*b1.z + a3.z*b2.z + a3.w*b3.z;
        acc3.w += a3.x*b0.w + a3.y*b1.w + a3.z*b2.w + a3.w*b3.w;
    }
    int gr = row0 + r0;
    if (gr + 0 < N) *(float4*)(H + (long)(gr + 0) * 64 + c0) = acc0;
    if (gr + 1 < N) *(float4*)(H + (long)(gr + 1) * 64 + c0) = acc1;
    if (gr + 2 < N) *(float4*)(H + (long)(gr + 2) * 64 + c0) = acc2;
    if (gr + 3 < N) *(float4*)(H + (long)(gr + 3) * 64 + c0) = acc3;
}

// ------- gather layer 1 (C=64) FUSED with layer-2 linear: h2 = relu(agg) @ W2 -------
// lane = g*16 + q : g = edge slot group (0..3), q = channel quarter (float4)
// After the xor-reduce all 64 lanes hold the full quarter-sum for their q, so
// every lane computes the relu'd row segment; then shfl-broadcast x LDS W2.
__global__ void k_gather1(const float* __restrict__ h1, const float* __restrict__ dis,
                          const int* __restrict__ rowptr, const int* __restrict__ deg,
                          const int* __restrict__ ecol,
                          const float* __restrict__ b1, const float* __restrict__ W2,
                          float* __restrict__ h2) {
    __shared__ float sW2[64 * 32];      // 8 KB; row stride 128B -> bank = col (2-way free)
    for (int i = threadIdx.x; i < 64 * 32; i += 256) sW2[i] = W2[i];
    __syncthreads();

    int node = (blockIdx.x << 2) + (threadIdx.x >> 6);
    int lane = threadIdx.x & 63;
    if (node >= N) return;                 // never taken: N % 4 == 0, grid = N/4
    int q = lane & 15;
    int g = lane >> 4;
    int start = rowptr[node];
    int dgr = deg[node];
    float di = dis[node];
    float4 acc = make_float4(0.f, 0.f, 0.f, 0.f);

    for (int base = 0; base < dgr; base += 64) {
        int cnt = min(dgr - base, 64);
        int se = 0; float we = 0.f;
        if (lane < cnt) { se = ecol[start + base + lane]; we = dis[se]; }
        for (int j = 0; j < cnt; j += 8) {
            int s0 = __shfl(se, j + g);       float w0 = __shfl(we, j + g);
            int s1 = __shfl(se, j + 4 + g);   float w1 = __shfl(we, j + 4 + g);
            float4 v0 = *(const float4*)(h1 + ((long)s0 << 6) + q * 4);
            float4 v1 = *(const float4*)(h1 + ((long)s1 << 6) + q * 4);
            acc.x += w0 * v0.x + w1 * v1.x;
            acc.y += w0 * v0.y + w1 * v1.y;
            acc.z += w0 * v0.z + w1 * v1.z;
            acc.w += w0 * v0.w + w1 * v1.w;
        }
    }
#pragma unroll
    for (int off = 16; off <= 32; off <<= 1) {
        acc.x += __shfl_xor(acc.x, off);
        acc.y += __shfl_xor(acc.y, off);
        acc.z += __shfl_xor(acc.z, off);
        acc.w += __shfl_xor(acc.w, off);
    }
    // all lanes: relu'd row segment for channels 4q..4q+3
    float4 hv = *(const float4*)(h1 + ((long)node << 6) + q * 4);
    float4 bb = *(const float4*)(b1 + q * 4);
    float4 r;
    r.x = fmaxf(di * (acc.x + di * hv.x) + bb.x, 0.f);
    r.y = fmaxf(di * (acc.y + di * hv.y) + bb.y, 0.f);
    r.z = fmaxf(di * (acc.z + di * hv.z) + bb.z, 0.f);
    r.w = fmaxf(di * (acc.w + di * hv.w) + bb.w, 0.f);
    // fused: h2[node][c] = sum_k row[k] * W2[k][c]; lanes<32 take k=0..31, lanes>=32 k=32..63
    int c = lane & 31;
    int k4base = (lane >> 5) * 8;          // 0 or 8
    float acc2 = 0.f;
#pragma unroll
    for (int i = 0; i < 8; ++i) {
        int k4 = k4base + i;
        float ax = __shfl(r.x, k4);        // row channel 4*k4+0
        float ay = __shfl(r.y, k4);
        float az = __shfl(r.z, k4);
        float aw = __shfl(r.w, k4);
        const float* wp = &sW2[(k4 * 4) * 32 + c];
        acc2 += ax * wp[0] + ay * wp[32] + az * wp[64] + aw * wp[96];
    }
    acc2 += __shfl_xor(acc2, 32);
    if (lane < 32) h2[(long)node * 32 + lane] = acc2;
}

// ---------------- gather layer 2 (C=32) + log_softmax: one wave per node ------
__global__ void k_gather2(const float* __restrict__ h2, const float* __restrict__ dis,
                          const int* __restrict__ rowptr, const int* __restrict__ deg,
                          const int* __restrict__ ecol,
                          const float* __restrict__ b2, float* __restrict__ out) {
    int node = (blockIdx.x << 2) + (threadIdx.x >> 6);
    int lane = threadIdx.x & 63;
    if (node >= N) return;
    int q = lane & 7;
    int g = lane >> 3;
    int start = rowptr[node];
    int dgr = deg[node];
    float di = dis[node];
    float4 acc = make_float4(0.f, 0.f, 0.f, 0.f);

    for (int base = 0; base < dgr; base += 64) {
        int cnt = min(dgr - base, 64);
        int se = 0; float we = 0.f;
        if (lane < cnt) { se = ecol[start + base + lane]; we = dis[se]; }
        for (int j = 0; j < cnt; j += 16) {
            int s0 = __shfl(se, j + g);       float w0 = __shfl(we, j + g);
            int s1 = __shfl(se, j + 8 + g);   float w1 = __shfl(we, j + 8 + g);
            float4 v0 = *(const float4*)(h2 + ((long)s0 << 5) + q * 4);
            float4 v1 = *(const float4*)(h2 + ((long)s1 << 5) + q * 4);
            acc.x += w0 * v0.x + w1 * v1.x;
            acc.y += w0 * v0.y + w1 * v1.y;
            acc.z += w0 * v0.z + w1 * v1.z;
            acc.w += w0 * v0.w + w1 * v1.w;
        }
    }
#pragma unroll
    for (int off = 8; off <= 32; off <<= 1) {
        acc.x += __shfl_xor(acc.x, off);
        acc.y += __shfl_xor(acc.y, off);
        acc.z += __shfl_xor(acc.z, off);
        acc.w += __shfl_xor(acc.w, off);
    }
    float4 hv = *(const float4*)(h2 + ((long)node << 5) + q * 4);
    float4 bb = *(const float4*)(b2 + q * 4);
    float4 v;
    v.x = di * (acc.x + di * hv.x) + bb.x;
    v.y = di * (acc.y + di * hv.y) + bb.y;
    v.z = di * (acc.z + di * hv.z) + bb.z;
    v.w = di * (acc.w + di * hv.w) + bb.w;
    float m = fmaxf(fmaxf(v.x, v.y), fmaxf(v.z, v.w));
#pragma unroll
    for (int off = 1; off <= 4; off <<= 1) m = fmaxf(m, __shfl_xor(m, off));
    float s = expf(v.x - m) + expf(v.y - m) + expf(v.z - m) + expf(v.w - m);
#pragma unroll
    for (int off = 1; off <= 4; off <<= 1) s += __shfl_xor(s, off);
    float lg = m + logf(s);
    if (g == 0) {
        float4 r;
        r.x = v.x - lg; r.y = v.y - lg; r.z = v.z - lg; r.w = v.w - lg;
        *(float4*)(out + ((long)node << 5) + q * 4) = r;
    }
}

extern "C" void kernel_launch(void* const* d_in, const int* in_sizes, int n_in,
                              void* d_out, int out_size, void* d_ws, size_t ws_size,
                              hipStream_t stream) {
    const float* x  = (const float*)d_in[0];
    const int*   ei = (const int*)d_in[1];
    const float* W1 = (const float*)d_in[2];
    const float* b1 = (const float*)d_in[3];
    const float* W2 = (const float*)d_in[4];
    const float* b2 = (const float*)d_in[5];
    float* out = (float*)d_out;

    const int* src = ei;
    const int* dst = ei + E;

    char* w = (char*)d_ws;
    int*   deg    = (int*)(w + 0);
    float* dis    = (float*)(w + (512u << 10));
    int*   rowptr = (int*)(w + (1024u << 10));
    int*   cursor = (int*)(w + (1536u << 10));
    int*   bsum   = (int*)(w + (2048u << 10));
    int*   ecol   = (int*)(w + (2560u << 10));
    float* h1     = (float*)(w + (10240u << 10));  // 25.6 MB
    float* h2     = (float*)(w + (36864u << 10));  // 12.8 MB (distinct from h1!)

    hipMemsetAsync(deg, 0, (size_t)N * 4, stream);
    k_degree<<<(E / 4 + 255) / 256, 256, 0, stream>>>(dst, deg);

    k_scanA<<<NB, 256, 0, stream>>>(deg, rowptr, bsum);
    k_scanC<<<(N + 255) / 256, 256, 0, stream>>>(rowptr, bsum, cursor, deg, dis);
    k_place<<<(E / 4 + 255) / 256, 256, 0, stream>>>(src, dst, cursor, ecol);

    k_gemm64<<<(N + 63) / 64, 256, 0, stream>>>(x, W1, h1);
    k_gather1<<<(N + 3) / 4, 256, 0, stream>>>(h1, dis, rowptr, deg, ecol, b1, W2, h2);

    k_gather2<<<(N + 3) / 4, 256, 0, stream>>>(h2, dis, rowptr, deg, ecol, b2, out);
}

// Round 9
// 212.764 us; speedup vs baseline: 1.0941x; 1.0941x over previous
//
#include <hip/hip_runtime.h>

// GCN 2-layer via CSR gather. Best-of-R7/R8: 4-edge ILP k_place, UNFUSED
// gather1 (W2-shfl fusion cost +39us VALU > agg1 roundtrip ~15us; reverted).
// GEMM k-loops kept ROLLED (#pragma unroll 1): full unroll -> 512 VGPR spill storm.
constexpr int N  = 100000;
constexpr int E  = 800000;
constexpr int CHUNK = 1024;
constexpr int NB = (N + CHUNK - 1) / CHUNK;   // 98 scan blocks

// ---------------- degree (4 edges/thread) ----------------
__global__ void k_degree(const int* __restrict__ dst, int* __restrict__ deg) {
    int t = blockIdx.x * blockDim.x + threadIdx.x;
    int e = t * 4;
    if (e + 3 < E) {
        int4 d4 = *(const int4*)(dst + e);
        atomicAdd(&deg[d4.x], 1);
        atomicAdd(&deg[d4.y], 1);
        atomicAdd(&deg[d4.z], 1);
        atomicAdd(&deg[d4.w], 1);
    } else {
        for (int k = e; k < E; ++k) atomicAdd(&deg[dst[k]], 1);
    }
}

// ---------------- exclusive scan of deg -> rowptr ----------------
__global__ void k_scanA(const int* __restrict__ deg, int* __restrict__ rowptr,
                        int* __restrict__ bsum) {
    __shared__ int a[2][256];
    int b = blockIdx.x, t = threadIdx.x;
    int base = b * CHUNK + t * 4;
    int v[4];
#pragma unroll
    for (int k = 0; k < 4; ++k) v[k] = (base + k < N) ? deg[base + k] : 0;
    int mysum = v[0] + v[1] + v[2] + v[3];
    a[0][t] = mysum;
    __syncthreads();
    int pin = 0;
    for (int off = 1; off < 256; off <<= 1) {
        int x = a[pin][t];
        if (t >= off) x += a[pin][t - off];
        a[pin ^ 1][t] = x;
        __syncthreads();
        pin ^= 1;
    }
    int incl = a[pin][t];
    int run = incl - mysum;
#pragma unroll
    for (int k = 0; k < 4; ++k) {
        if (base + k < N) rowptr[base + k] = run;
        run += v[k];
    }
    if (t == 255) bsum[b] = incl;
}

// scanC: adds global chunk offset (computed in-block from bsum), writes cursor + dis
__global__ void k_scanC(int* __restrict__ rowptr, const int* __restrict__ bsum,
                        int* __restrict__ cursor, const int* __restrict__ deg,
                        float* __restrict__ dis) {
    __shared__ int s_off;
    int cid = blockIdx.x >> 2;            // 256-node block -> 1024-node chunk
    if (threadIdx.x == 0) {
        int run = 0;
        for (int i = 0; i < cid; ++i) run += bsum[i];
        s_off = run;
    }
    __syncthreads();
    int i = blockIdx.x * blockDim.x + threadIdx.x;
    if (i < N) {
        int r = rowptr[i] + s_off;
        rowptr[i] = r;
        cursor[i] = r;
        dis[i] = rsqrtf((float)(deg[i] + 1));   // +1 self-loop
    }
}

// ---------------- CSR placement: 4 edges/thread, 4 independent atomic chains --
__global__ void k_place(const int* __restrict__ src, const int* __restrict__ dst,
                        int* __restrict__ cursor, int* __restrict__ ecol) {
    int t = blockIdx.x * blockDim.x + threadIdx.x;
    int e = t * 4;
    if (e + 3 < E) {
        int4 s4 = *(const int4*)(src + e);
        int4 d4 = *(const int4*)(dst + e);
        int p0 = atomicAdd(&cursor[d4.x], 1);
        int p1 = atomicAdd(&cursor[d4.y], 1);
        int p2 = atomicAdd(&cursor[d4.z], 1);
        int p3 = atomicAdd(&cursor[d4.w], 1);
        ecol[p0] = s4.x;
        ecol[p1] = s4.y;
        ecol[p2] = s4.z;
        ecol[p3] = s4.w;
    } else {
        for (int k = e; k < E; ++k) {
            int pos = atomicAdd(&cursor[dst[k]], 1);
            ecol[pos] = src[k];
        }
    }
}

// ---------------- GEMM 64->64: H[N,64] = X[N,64] @ W[64,64] ----------------
__global__ __launch_bounds__(256, 2)
void k_gemm64(const float* __restrict__ X, const float* __restrict__ W,
              float* __restrict__ H) {
    __shared__ float sX[64][68];    // 272B rows: float4-aligned, 2-way banks (free)
    __shared__ float sW[64 * 64];
    int row0 = blockIdx.x * 64;
    for (int i = threadIdx.x; i < 64 * 64; i += 256) sW[i] = W[i];
    for (int i4 = threadIdx.x; i4 < 64 * 16; i4 += 256) {
        int r = i4 >> 4, c4 = i4 & 15;
        int gr = row0 + r;
        float4 v = make_float4(0.f, 0.f, 0.f, 0.f);
        if (gr < N) v = *(const float4*)(X + (long)gr * 64 + c4 * 4);
        *(float4*)&sX[r][c4 * 4] = v;
    }
    __syncthreads();

    int ty = threadIdx.x >> 4, tx = threadIdx.x & 15;
    int r0 = ty * 4, c0 = tx * 4;
    float4 acc0 = make_float4(0.f, 0.f, 0.f, 0.f);
    float4 acc1 = acc0, acc2 = acc0, acc3 = acc0;

#pragma unroll 1
    for (int k = 0; k < 64; k += 4) {
        float4 a0 = *(const float4*)&sX[r0 + 0][k];
        float4 a1 = *(const float4*)&sX[r0 + 1][k];
        float4 a2 = *(const float4*)&sX[r0 + 2][k];
        float4 a3 = *(const float4*)&sX[r0 + 3][k];
        float4 b0 = *(const float4*)&sW[(k + 0) * 64 + c0];
        float4 b1 = *(const float4*)&sW[(k + 1) * 64 + c0];
        float4 b2 = *(const float4*)&sW[(k + 2) * 64 + c0];
        float4 b3 = *(const float4*)&sW[(k + 3) * 64 + c0];
        acc0.x += a0.x*b0.x + a0.y*b1.x + a0.z*b2.x + a0.w*b3.x;
        acc0.y += a0.x*b0.y + a0.y*b1.y + a0.z*b2.y + a0.w*b3.y;
        acc0.z += a0.x*b0.z + a0.y*b1.z + a0.z*b2.z + a0.w*b3.z;
        acc0.w += a0.x*b0.w + a0.y*b1.w + a0.z*b2.w + a0.w*b3.w;
        acc1.x += a1.x*b0.x + a1.y*b1.x + a1.z*b2.x + a1.w*b3.x;
        acc1.y += a1.x*b0.y + a1.y*b1.y + a1.z*b2.y + a1.w*b3.y;
        acc1.z += a1.x*b0.z + a1.y*b1.z + a1.z*b2.z + a1.w*b3.z;
        acc1.w += a1.x*b0.w + a1.y*b1.w + a1.z*b2.w + a1.w*b3.w;
        acc2.x += a2.x*b0.x + a2.y*b1.x + a2.z*b2.x + a2.w*b3.x;
        acc2.y += a2.x*b0.y + a2.y*b1.y + a2.z*b2.y + a2.w*b3.y;
        acc2.z += a2.x*b0.z + a2.y*b1.z + a2.z*b2.z + a2.w*b3.z;
        acc2.w += a2.x*b0.w + a2.y*b1.w + a2.z*b2.w + a2.w*b3.w;
        acc3.x += a3.x*b0.x + a3.y*b1.x + a3.z*b2.x + a3.w*b3.x;
        acc3.y += a3.x*b0.y + a3.y*b1.y + a3.z*b2.y + a3.w*b3.y;
        acc3.z += a3.x*b0.z + a3.y*b1.z + a3.z*b2.z + a3.w*b3.z;
        acc3.w += a3.x*b0.w + a3.y*b1.w + a3.z*b2.w + a3.w*b3.w;
    }
    int gr = row0 + r0;
    if (gr + 0 < N) *(float4*)(H + (long)(gr + 0) * 64 + c0) = acc0;
    if (gr + 1 < N) *(float4*)(H + (long)(gr + 1) * 64 + c0) = acc1;
    if (gr + 2 < N) *(float4*)(H + (long)(gr + 2) * 64 + c0) = acc2;
    if (gr + 3 < N) *(float4*)(H + (long)(gr + 3) * 64 + c0) = acc3;
}

// ---------------- GEMM 64->32: H[N,32] = X[N,64] @ W[64,32] ----------------
__global__ __launch_bounds__(256, 2)
void k_gemm32(const float* __restrict__ X, const float* __restrict__ W,
              float* __restrict__ H) {
    __shared__ float sX[64][68];
    __shared__ float sW[64 * 32];
    int row0 = blockIdx.x * 64;
    for (int i = threadIdx.x; i < 64 * 32; i += 256) sW[i] = W[i];
    for (int i4 = threadIdx.x; i4 < 64 * 16; i4 += 256) {
        int r = i4 >> 4, c4 = i4 & 15;
        int gr = row0 + r;
        float4 v = make_float4(0.f, 0.f, 0.f, 0.f);
        if (gr < N) v = *(const float4*)(X + (long)gr * 64 + c4 * 4);
        *(float4*)&sX[r][c4 * 4] = v;
    }
    __syncthreads();

    int ty = threadIdx.x >> 4, tx = threadIdx.x & 15;
    int r0 = ty * 4, c0 = tx * 2;
    float2 acc0 = make_float2(0.f, 0.f);
    float2 acc1 = acc0, acc2 = acc0, acc3 = acc0;

#pragma unroll 1
    for (int k = 0; k < 64; k += 4) {
        float4 a0 = *(const float4*)&sX[r0 + 0][k];
        float4 a1 = *(const float4*)&sX[r0 + 1][k];
        float4 a2 = *(const float4*)&sX[r0 + 2][k];
        float4 a3 = *(const float4*)&sX[r0 + 3][k];
        float2 b0 = *(const float2*)&sW[(k + 0) * 32 + c0];
        float2 b1 = *(const float2*)&sW[(k + 1) * 32 + c0];
        float2 b2 = *(const float2*)&sW[(k + 2) * 32 + c0];
        float2 b3 = *(const float2*)&sW[(k + 3) * 32 + c0];
        acc0.x += a0.x*b0.x + a0.y*b1.x + a0.z*b2.x + a0.w*b3.x;
        acc0.y += a0.x*b0.y + a0.y*b1.y + a0.z*b2.y + a0.w*b3.y;
        acc1.x += a1.x*b0.x + a1.y*b1.x + a1.z*b2.x + a1.w*b3.x;
        acc1.y += a1.x*b0.y + a1.y*b1.y + a1.z*b2.y + a1.w*b3.y;
        acc2.x += a2.x*b0.x + a2.y*b1.x + a2.z*b2.x + a2.w*b3.x;
        acc2.y += a2.x*b0.y + a2.y*b1.y + a2.z*b2.y + a2.w*b3.y;
        acc3.x += a3.x*b0.x + a3.y*b1.x + a3.z*b2.x + a3.w*b3.x;
        acc3.y += a3.x*b0.y + a3.y*b1.y + a3.z*b2.y + a3.w*b3.y;
    }
    int gr = row0 + r0;
    if (gr + 0 < N) *(float2*)(H + (long)(gr + 0) * 32 + c0) = acc0;
    if (gr + 1 < N) *(float2*)(H + (long)(gr + 1) * 32 + c0) = acc1;
    if (gr + 2 < N) *(float2*)(H + (long)(gr + 2) * 32 + c0) = acc2;
    if (gr + 3 < N) *(float2*)(H + (long)(gr + 3) * 32 + c0) = acc3;
}

// ---------------- gather layer 1 (C=64): one wave per node ----------------
// lane = g*16 + q : g = edge slot group (0..3), q = channel quarter (float4)
// All __shfl ops execute with FULL exec mask; lanes >= cnt hold se=0,we=0.
__global__ void k_gather1(const float* __restrict__ h1, const float* __restrict__ dis,
                          const int* __restrict__ rowptr, const int* __restrict__ deg,
                          const int* __restrict__ ecol,
                          const float* __restrict__ b1, float* __restrict__ agg1) {
    int node = (blockIdx.x << 2) + (threadIdx.x >> 6);
    int lane = threadIdx.x & 63;
    if (node >= N) return;                 // wave-uniform (N % 4 == 0)
    int q = lane & 15;
    int g = lane >> 4;
    int start = rowptr[node];
    int dgr = deg[node];
    float di = dis[node];
    float4 acc = make_float4(0.f, 0.f, 0.f, 0.f);

    for (int base = 0; base < dgr; base += 64) {
        int cnt = min(dgr - base, 64);
        int se = 0; float we = 0.f;
        if (lane < cnt) { se = ecol[start + base + lane]; we = dis[se]; }
        for (int j = 0; j < cnt; j += 8) {
            int s0 = __shfl(se, j + g);       float w0 = __shfl(we, j + g);
            int s1 = __shfl(se, j + 4 + g);   float w1 = __shfl(we, j + 4 + g);
            float4 v0 = *(const float4*)(h1 + ((long)s0 << 6) + q * 4);
            float4 v1 = *(const float4*)(h1 + ((long)s1 << 6) + q * 4);
            acc.x += w0 * v0.x + w1 * v1.x;
            acc.y += w0 * v0.y + w1 * v1.y;
            acc.z += w0 * v0.z + w1 * v1.z;
            acc.w += w0 * v0.w + w1 * v1.w;
        }
    }
#pragma unroll
    for (int off = 16; off <= 32; off <<= 1) {
        acc.x += __shfl_xor(acc.x, off);
        acc.y += __shfl_xor(acc.y, off);
        acc.z += __shfl_xor(acc.z, off);
        acc.w += __shfl_xor(acc.w, off);
    }
    if (g == 0) {
        float4 hv = *(const float4*)(h1 + ((long)node << 6) + q * 4);
        float4 bb = *(const float4*)(b1 + q * 4);
        float4 r;
        r.x = fmaxf(di * (acc.x + di * hv.x) + bb.x, 0.f);
        r.y = fmaxf(di * (acc.y + di * hv.y) + bb.y, 0.f);
        r.z = fmaxf(di * (acc.z + di * hv.z) + bb.z, 0.f);
        r.w = fmaxf(di * (acc.w + di * hv.w) + bb.w, 0.f);
        *(float4*)(agg1 + ((long)node << 6) + q * 4) = r;
    }
}

// ---------------- gather layer 2 (C=32) + log_softmax: one wave per node ------
__global__ void k_gather2(const float* __restrict__ h2, const float* __restrict__ dis,
                          const int* __restrict__ rowptr, const int* __restrict__ deg,
                          const int* __restrict__ ecol,
                          const float* __restrict__ b2, float* __restrict__ out) {
    int node = (blockIdx.x << 2) + (threadIdx.x >> 6);
    int lane = threadIdx.x & 63;
    if (node >= N) return;
    int q = lane & 7;
    int g = lane >> 3;
    int start = rowptr[node];
    int dgr = deg[node];
    float di = dis[node];
    float4 acc = make_float4(0.f, 0.f, 0.f, 0.f);

    for (int base = 0; base < dgr; base += 64) {
        int cnt = min(dgr - base, 64);
        int se = 0; float we = 0.f;
        if (lane < cnt) { se = ecol[start + base + lane]; we = dis[se]; }
        for (int j = 0; j < cnt; j += 16) {
            int s0 = __shfl(se, j + g);       float w0 = __shfl(we, j + g);
            int s1 = __shfl(se, j + 8 + g);   float w1 = __shfl(we, j + 8 + g);
            float4 v0 = *(const float4*)(h2 + ((long)s0 << 5) + q * 4);
            float4 v1 = *(const float4*)(h2 + ((long)s1 << 5) + q * 4);
            acc.x += w0 * v0.x + w1 * v1.x;
            acc.y += w0 * v0.y + w1 * v1.y;
            acc.z += w0 * v0.z + w1 * v1.z;
            acc.w += w0 * v0.w + w1 * v1.w;
        }
    }
#pragma unroll
    for (int off = 8; off <= 32; off <<= 1) {
        acc.x += __shfl_xor(acc.x, off);
        acc.y += __shfl_xor(acc.y, off);
        acc.z += __shfl_xor(acc.z, off);
        acc.w += __shfl_xor(acc.w, off);
    }
    float4 hv = *(const float4*)(h2 + ((long)node << 5) + q * 4);
    float4 bb = *(const float4*)(b2 + q * 4);
    float4 v;
    v.x = di * (acc.x + di * hv.x) + bb.x;
    v.y = di * (acc.y + di * hv.y) + bb.y;
    v.z = di * (acc.z + di * hv.z) + bb.z;
    v.w = di * (acc.w + di * hv.w) + bb.w;
    float m = fmaxf(fmaxf(v.x, v.y), fmaxf(v.z, v.w));
#pragma unroll
    for (int off = 1; off <= 4; off <<= 1) m = fmaxf(m, __shfl_xor(m, off));
    float s = expf(v.x - m) + expf(v.y - m) + expf(v.z - m) + expf(v.w - m);
#pragma unroll
    for (int off = 1; off <= 4; off <<= 1) s += __shfl_xor(s, off);
    float lg = m + logf(s);
    if (g == 0) {
        float4 r;
        r.x = v.x - lg; r.y = v.y - lg; r.z = v.z - lg; r.w = v.w - lg;
        *(float4*)(out + ((long)node << 5) + q * 4) = r;
    }
}

extern "C" void kernel_launch(void* const* d_in, const int* in_sizes, int n_in,
                              void* d_out, int out_size, void* d_ws, size_t ws_size,
                              hipStream_t stream) {
    const float* x  = (const float*)d_in[0];
    const int*   ei = (const int*)d_in[1];
    const float* W1 = (const float*)d_in[2];
    const float* b1 = (const float*)d_in[3];
    const float* W2 = (const float*)d_in[4];
    const float* b2 = (const float*)d_in[5];
    float* out = (float*)d_out;

    const int* src = ei;
    const int* dst = ei + E;

    char* w = (char*)d_ws;
    int*   deg    = (int*)(w + 0);
    float* dis    = (float*)(w + (512u << 10));
    int*   rowptr = (int*)(w + (1024u << 10));
    int*   cursor = (int*)(w + (1536u << 10));
    int*   bsum   = (int*)(w + (2048u << 10));
    int*   ecol   = (int*)(w + (2560u << 10));
    float* h1     = (float*)(w + (10240u << 10));  // 25.6 MB (reused as h2)
    float* agg1   = (float*)(w + (36864u << 10));  // 25.6 MB
    float* h2     = h1;                            // h1 dead after gather1

    hipMemsetAsync(deg, 0, (size_t)N * 4, stream);
    k_degree<<<(E / 4 + 255) / 256, 256, 0, stream>>>(dst, deg);

    k_scanA<<<NB, 256, 0, stream>>>(deg, rowptr, bsum);
    k_scanC<<<(N + 255) / 256, 256, 0, stream>>>(rowptr, bsum, cursor, deg, dis);
    k_place<<<(E / 4 + 255) / 256, 256, 0, stream>>>(src, dst, cursor, ecol);

    k_gemm64<<<(N + 63) / 64, 256, 0, stream>>>(x, W1, h1);
    k_gather1<<<(N + 3) / 4, 256, 0, stream>>>(h1, dis, rowptr, deg, ecol, b1, agg1);

    k_gemm32<<<(N + 63) / 64, 256, 0, stream>>>(agg1, W2, h2);
    k_gather2<<<(N + 3) / 4, 256, 0, stream>>>(h2, dis, rowptr, deg, ecol, b2, out);
}